// Round 6
// baseline (2746.233 us; speedup 1.0000x reference)
//
#include <hip/hip_runtime.h>
#include <hip/hip_bf16.h>

typedef __attribute__((ext_vector_type(8))) short bf16x8;
typedef __attribute__((ext_vector_type(4))) float f32x4;
typedef __attribute__((ext_vector_type(4))) unsigned short u16x4;

#define HB 256      // hidden
#define G3 768      // 3*H
#define SQ 512      // seq len
#define NBATCH 4
#define NV 32000

__device__ __forceinline__ unsigned short f2bf(float f) {
    unsigned int u = __float_as_uint(f);
    u = u + 0x7FFFu + ((u >> 16) & 1u);   // RNE
    return (unsigned short)(u >> 16);
}
__device__ __forceinline__ float sigm(float x) {
    return 1.0f / (1.0f + __expf(-x));
}
__device__ __forceinline__ float tanh_fast(float x) {
    // safe at +/-inf: 1 - 2/(e^{2x}+1)
    return 1.0f - 2.0f / (__expf(2.0f * x) + 1.0f);
}

// ---------------------------------------------------------------- K0: prep
// (a) W_ih^T fp32 [256][768] for coalesced K1 loads
// (b) W_hh -> bf16 MFMA A-fragments for the 8-wave k_gru:
//     layout [w:8][t:3][rt:2][c:8][lane:64][i:8]
//     wave w owns hidden rows 32w..32w+31 (two 16-row tiles rt) per gate t
// (c) W_out -> bf16 (optional, if ws large enough)
__global__ void k_prep(const float* __restrict__ W_ih, const float* __restrict__ W_hh,
                       const float* __restrict__ W_out, float* __restrict__ w_ihT,
                       unsigned short* __restrict__ wfrag, unsigned short* __restrict__ woutbf,
                       int do_wout) {
    int stride = gridDim.x * blockDim.x;
    int tid = blockIdx.x * blockDim.x + threadIdx.x;
    for (int e = tid; e < G3 * HB; e += stride) {
        int k = e / G3, g = e - k * G3;
        w_ihT[e] = W_ih[g * HB + k];
    }
    for (int e = tid; e < G3 * HB; e += stride) {
        int i = e & 7, l = (e >> 3) & 63, c = (e >> 9) & 7, rt = (e >> 12) & 1;
        int q = e >> 13;              // 0..23
        int t = q % 3, w = q / 3;     // gate, wave
        int row = t * 256 + 32 * w + 16 * rt + (l & 15);
        int kk = 32 * c + 8 * (l >> 4) + i;
        wfrag[e] = f2bf(W_hh[row * HB + kk]);
    }
    if (do_wout) {
        for (int e = tid; e < NV * HB; e += stride) woutbf[e] = f2bf(W_out[e]);
    }
}

// ---------------------------------------------------------------- K1: embed + xp
__global__ __launch_bounds__(256) void k_embed_xp(
        const int* __restrict__ x, const float* __restrict__ emb,
        const float* __restrict__ w_ihT, const float* __restrict__ b_ih,
        const float* __restrict__ b_hh, float* __restrict__ xp) {
    __shared__ float e[8][HB];
    int tid = threadIdx.x;
    int tok0 = blockIdx.x * 8;
    {
        int s = tid >> 5, k0 = (tid & 31) * 8;
        long idx = x[tok0 + s];
        const float* src = emb + idx * (long)HB + k0;
        f32x4 a = *(const f32x4*)src, bq = *(const f32x4*)(src + 4);
        *(f32x4*)&e[s][k0] = a;
        *(f32x4*)&e[s][k0 + 4] = bq;
    }
    __syncthreads();
    #pragma unroll
    for (int it = 0; it < 3; ++it) {
        int gg = tid + it * 256;
        float acc[8] = {0.f, 0.f, 0.f, 0.f, 0.f, 0.f, 0.f, 0.f};
        for (int k = 0; k < HB; k += 4) {
            float w0 = w_ihT[(k + 0) * G3 + gg];
            float w1 = w_ihT[(k + 1) * G3 + gg];
            float w2 = w_ihT[(k + 2) * G3 + gg];
            float w3 = w_ihT[(k + 3) * G3 + gg];
            #pragma unroll
            for (int s = 0; s < 8; ++s) {
                f32x4 ev = *(const f32x4*)&e[s][k];
                acc[s] += w0 * ev.x + w1 * ev.y + w2 * ev.z + w3 * ev.w;
            }
        }
        float bias = b_ih[gg] + (gg < 512 ? b_hh[gg] : 0.f);
        #pragma unroll
        for (int s = 0; s < 8; ++s)
            xp[(size_t)(tok0 + s) * G3 + gg] = acc[s] + bias;
    }
}

// ---------------------------------------------------------------- K2: GRU scan
// One workgroup, 8 waves, 2 waves/SIMD (256 unified-reg budget via
// amdgpu_waves_per_eu(2,2)). W_hh A-fragments (192) + accumulators (12) live
// in AGPRs through inline-asm "a" constraints; VGPR side ~50 -> no spill.
// Per step (ONE barrier):
//   6x global_load_dwordx4 of xp (per-lane, L2/L3-hit; hides under MFMAs)
//   rt=0: 24 MFMA -> gate math in-lane (C rows 4hi+j == lane's W rows) -> h
//   rt=1: same; h written bf16 to double-buffered swizzled hbf + global rnn.
__global__ __attribute__((amdgpu_waves_per_eu(2, 2))) __launch_bounds__(512)
void k_gru(const float* __restrict__ xp, const unsigned short* __restrict__ wfrag,
           const float* __restrict__ b_hh, unsigned short* __restrict__ rnn) {
    __shared__ unsigned short hbf[2][NBATCH][HB];    // 4096 B, XOR-swizzled
    __shared__ float bnL[HB];                        // 1024 B

    int tid = threadIdx.x;
    int w = tid >> 6, l = tid & 63;
    int c15 = l & 15, hi = l >> 4;
    int b4 = c15 & 3;
    int swz = (b4 & 1) << 6;

    // 48 A-fragments (lane-contiguous 16B loads); pinned to AGPRs once,
    // all MFMA uses are "a" operands -> resident for the whole scan.
    bf16x8 A[3][2][8];
    #pragma unroll
    for (int t3 = 0; t3 < 3; ++t3)
        #pragma unroll
        for (int rt = 0; rt < 2; ++rt)
            #pragma unroll
            for (int c = 0; c < 8; ++c)
                A[t3][rt][c] = ((const bf16x8*)wfrag)[(((w * 3 + t3) * 2 + rt) * 8 + c) * 64 + l];
    #pragma unroll
    for (int t3 = 0; t3 < 3; ++t3)
        #pragma unroll
        for (int rt = 0; rt < 2; ++rt)
            #pragma unroll
            for (int c = 0; c < 8; ++c)
                asm volatile("" : "+a"(A[t3][rt][c]));

    for (int k = tid; k < 2 * NBATCH * HB; k += 512) ((unsigned short*)hbf)[k] = 0;
    if (tid < HB) bnL[tid] = b_hh[512 + tid];
    __syncthreads();

    f32x4 h0 = {0.f, 0.f, 0.f, 0.f}, h1 = {0.f, 0.f, 0.f, 0.f};
    const f32x4 zz = {0.f, 0.f, 0.f, 0.f};

    int i0 = 32 * w + 4 * hi;                               // rt=0 row base
    const float* xpb = xp + (size_t)b4 * SQ * G3 + i0;      // += G3 per step
    unsigned short* rnb = rnn + (size_t)b4 * SQ * HB + i0;  // += HB per step

    for (int t = 0; t < SQ; ++t) {
        int cur = t & 1, nxt = cur ^ 1;
        // xp for this step: issued before the MFMA cluster, consumed after.
        f32x4 xr0 = *(const f32x4*)(xpb);
        f32x4 xr1 = *(const f32x4*)(xpb + 16);
        f32x4 xz0 = *(const f32x4*)(xpb + 256);
        f32x4 xz1 = *(const f32x4*)(xpb + 256 + 16);
        f32x4 xn0 = *(const f32x4*)(xpb + 512);
        f32x4 xn1 = *(const f32x4*)(xpb + 512 + 16);

        const char* hbb = (const char*)hbf + cur * 2048 + b4 * 512;

        #pragma unroll
        for (int rt = 0; rt < 2; ++rt) {
            f32x4 acc[3];
            acc[0] = zz; acc[1] = zz; acc[2] = zz;
            #pragma unroll
            for (int c = 0; c < 8; ++c) {
                bf16x8 Bf = *(const bf16x8*)(hbb + ((64 * c + 16 * hi) ^ swz));
                asm("v_mfma_f32_16x16x32_bf16 %0, %1, %2, %0"
                    : "+a"(acc[0]) : "a"(A[0][rt][c]), "v"(Bf));
                asm("v_mfma_f32_16x16x32_bf16 %0, %1, %2, %0"
                    : "+a"(acc[1]) : "a"(A[1][rt][c]), "v"(Bf));
                asm("v_mfma_f32_16x16x32_bf16 %0, %1, %2, %0"
                    : "+a"(acc[2]) : "a"(A[2][rt][c]), "v"(Bf));
            }
            // gate math: lane (c15,hi) owns rows i0 + 16rt + j, batch b4
            int i0rt = i0 + 16 * rt;
            f32x4 xr = rt ? xr1 : xr0;
            f32x4 xz = rt ? xz1 : xz0;
            f32x4 xn = rt ? xn1 : xn0;
            f32x4 bnv = *(const f32x4*)&bnL[i0rt];
            f32x4& H = rt ? h1 : h0;
            u16x4 pack;
            #pragma unroll
            for (int j = 0; j < 4; ++j) {
                float r = sigm(xr[j] + acc[0][j]);
                float z = sigm(xz[j] + acc[1][j]);
                float n = tanh_fast(xn[j] + r * (acc[2][j] + bnv[j]));
                float hv = (1.f - z) * n + z * H[j];
                H[j] = hv;
                pack[j] = f2bf(hv);
            }
            if (c15 < 4) {
                *(u16x4*)((char*)hbf + nxt * 2048 + b4 * 512 + ((i0rt * 2) ^ swz)) = pack;
                *(u16x4*)(rnb + 16 * rt) = pack;
            }
        }
        __syncthreads();
        xpb += G3;
        rnb += HB;
    }
}

// ---------------------------------------------------------------- K3: logits
// [2048,256] bf16 @ [256,32000] bf16 -> fp32 + bias + mask. No LDS: A (1 MB)
// and B (16 MB) are L2/L3 resident; HBM-write-bound.
template <int CONV>
__global__ __launch_bounds__(256) void k_logits(
        const unsigned short* __restrict__ rnn, const unsigned short* __restrict__ woutbf,
        const float* __restrict__ woutf, const float* __restrict__ b_out,
        const int* __restrict__ x, float* __restrict__ out) {
    int tid = threadIdx.x;
    int wv = tid >> 6, l = tid & 63;
    int wm = wv >> 1, wn = wv & 1;
    int c15 = l & 15, hi = l >> 4;
    int m0 = blockIdx.y * 128 + wm * 64;
    int n0 = blockIdx.x * 128 + wn * 64;

    const f32x4 zz = {0.f, 0.f, 0.f, 0.f};
    f32x4 acc[4][4];
    #pragma unroll
    for (int i = 0; i < 4; ++i)
        #pragma unroll
        for (int j = 0; j < 4; ++j) acc[i][j] = zz;

    #pragma unroll
    for (int c = 0; c < 8; ++c) {
        bf16x8 af[4], bfr[4];
        #pragma unroll
        for (int rt = 0; rt < 4; ++rt)
            af[rt] = *(const bf16x8*)(rnn + (size_t)(m0 + rt * 16 + c15) * HB + 32 * c + 8 * hi);
        #pragma unroll
        for (int ct = 0; ct < 4; ++ct) {
            if (CONV) {
                const float* s = woutf + (size_t)(n0 + ct * 16 + c15) * HB + 32 * c + 8 * hi;
                f32x4 lo = *(const f32x4*)s, hi4 = *(const f32x4*)(s + 4);
                bf16x8 bb;
                #pragma unroll
                for (int q = 0; q < 4; ++q) bb[q] = (short)f2bf(lo[q]);
                #pragma unroll
                for (int q = 0; q < 4; ++q) bb[4 + q] = (short)f2bf(hi4[q]);
                bfr[ct] = bb;
            } else {
                bfr[ct] = *(const bf16x8*)(woutbf + (size_t)(n0 + ct * 16 + c15) * HB + 32 * c + 8 * hi);
            }
        }
        #pragma unroll
        for (int rt = 0; rt < 4; ++rt)
            #pragma unroll
            for (int ct = 0; ct < 4; ++ct)
                acc[rt][ct] = __builtin_amdgcn_mfma_f32_16x16x32_bf16(af[rt], bfr[ct], acc[rt][ct], 0, 0, 0);
    }

    float bo[4];
    #pragma unroll
    for (int ct = 0; ct < 4; ++ct) bo[ct] = b_out[n0 + ct * 16 + c15];

    const float NEGINF = -__builtin_inff();
    #pragma unroll
    for (int rt = 0; rt < 4; ++rt) {
        #pragma unroll
        for (int j = 0; j < 4; ++j) {
            int m = m0 + rt * 16 + 4 * hi + j;
            int tt = m & (SQ - 1);
            bool bad = (tt > 0) && (x[m - 1] == 0);
            float* orow = out + (size_t)m * NV;
            #pragma unroll
            for (int ct = 0; ct < 4; ++ct) {
                int v = n0 + ct * 16 + c15;
                float val = acc[rt][ct][j] + bo[ct];
                if (bad && v >= 3) val = NEGINF;
                orow[v] = val;
            }
        }
    }
}

extern "C" void kernel_launch(void* const* d_in, const int* in_sizes, int n_in,
                              void* d_out, int out_size, void* d_ws, size_t ws_size,
                              hipStream_t stream) {
    const int*   x     = (const int*)d_in[0];
    const float* emb   = (const float*)d_in[1];
    const float* W_ih  = (const float*)d_in[2];
    const float* W_hh  = (const float*)d_in[3];
    const float* b_ih  = (const float*)d_in[4];
    const float* b_hh  = (const float*)d_in[5];
    const float* W_out = (const float*)d_in[6];
    const float* b_out = (const float*)d_in[7];
    float* out = (float*)d_out;

    char* ws = (char*)d_ws;
    float*          xp     = (float*)(ws);                       // 6,291,456 B
    float*          w_ihT  = (float*)(ws + 6291456);             // 786,432 B
    unsigned short* wfrag  = (unsigned short*)(ws + 7077888);    // 393,216 B
    unsigned short* rnn    = (unsigned short*)(ws + 7471104);    // 1,048,576 B
    unsigned short* woutbf = (unsigned short*)(ws + 8519680);    // 16,384,000 B
    int use_woutbf = (ws_size >= (size_t)24903680) ? 1 : 0;

    k_prep<<<2048, 256, 0, stream>>>(W_ih, W_hh, W_out, w_ihT, wfrag, woutbf, use_woutbf);
    k_embed_xp<<<256, 256, 0, stream>>>(x, emb, w_ihT, b_ih, b_hh, xp);
    k_gru<<<1, 512, 0, stream>>>(xp, wfrag, b_hh, rnn);
    dim3 g3(NV / 128, 2048 / 128);
    if (use_woutbf)
        k_logits<0><<<g3, 256, 0, stream>>>(rnn, woutbf, nullptr, b_out, x, out);
    else
        k_logits<1><<<g3, 256, 0, stream>>>(rnn, nullptr, W_out, b_out, x, out);
}

// Round 7
// 1904.150 us; speedup vs baseline: 1.4422x; 1.4422x over previous
//
#include <hip/hip_runtime.h>
#include <hip/hip_bf16.h>

typedef __attribute__((ext_vector_type(8))) short bf16x8;
typedef __attribute__((ext_vector_type(4))) float f32x4;
typedef __attribute__((ext_vector_type(4))) unsigned short u16x4;

#define HB 256      // hidden
#define G3 768      // 3*H
#define SQ 512      // seq len
#define NBATCH 4
#define NV 32000

__device__ __forceinline__ unsigned short f2bf(float f) {
    unsigned int u = __float_as_uint(f);
    u = u + 0x7FFFu + ((u >> 16) & 1u);   // RNE
    return (unsigned short)(u >> 16);
}
__device__ __forceinline__ float sigm(float x) {
    return 1.0f / (1.0f + __expf(-x));
}
__device__ __forceinline__ float tanh_fast(float x) {
    // safe at +/-inf: 1 - 2/(e^{2x}+1)
    return 1.0f - 2.0f / (__expf(2.0f * x) + 1.0f);
}

// ---------------------------------------------------------------- K0: prep
// (a) W_ih^T fp32 [256][768] for coalesced K1 loads
// (b) W_hh -> bf16 MFMA A-fragments for the 4-wave k_gru:
//     layout [w:4][g:3][s:4][c:8][lane:64][i:8]
//     wave w owns hidden rows 64w..64w+63 (four 16-row subtiles s) per gate g
// (c) W_out -> bf16 (optional, if ws large enough)
__global__ void k_prep(const float* __restrict__ W_ih, const float* __restrict__ W_hh,
                       const float* __restrict__ W_out, float* __restrict__ w_ihT,
                       unsigned short* __restrict__ wfrag, unsigned short* __restrict__ woutbf,
                       int do_wout) {
    int stride = gridDim.x * blockDim.x;
    int tid = blockIdx.x * blockDim.x + threadIdx.x;
    for (int e = tid; e < G3 * HB; e += stride) {
        int k = e / G3, g = e - k * G3;
        w_ihT[e] = W_ih[g * HB + k];
    }
    for (int e = tid; e < G3 * HB; e += stride) {
        int i = e & 7, l = (e >> 3) & 63, c = (e >> 9) & 7, s = (e >> 12) & 3;
        int q = e >> 14;              // 0..11
        int g = q % 3, w = q / 3;     // gate, wave
        int row = g * 256 + 64 * w + 16 * s + (l & 15);
        int kk = 32 * c + 8 * (l >> 4) + i;
        wfrag[e] = f2bf(W_hh[row * HB + kk]);
    }
    if (do_wout) {
        for (int e = tid; e < NV * HB; e += stride) woutbf[e] = f2bf(W_out[e]);
    }
}

// ---------------------------------------------------------------- K1: embed + xp
__global__ __launch_bounds__(256) void k_embed_xp(
        const int* __restrict__ x, const float* __restrict__ emb,
        const float* __restrict__ w_ihT, const float* __restrict__ b_ih,
        const float* __restrict__ b_hh, float* __restrict__ xp) {
    __shared__ float e[8][HB];
    int tid = threadIdx.x;
    int tok0 = blockIdx.x * 8;
    {
        int s = tid >> 5, k0 = (tid & 31) * 8;
        long idx = x[tok0 + s];
        const float* src = emb + idx * (long)HB + k0;
        f32x4 a = *(const f32x4*)src, bq = *(const f32x4*)(src + 4);
        *(f32x4*)&e[s][k0] = a;
        *(f32x4*)&e[s][k0 + 4] = bq;
    }
    __syncthreads();
    #pragma unroll
    for (int it = 0; it < 3; ++it) {
        int gg = tid + it * 256;
        float acc[8] = {0.f, 0.f, 0.f, 0.f, 0.f, 0.f, 0.f, 0.f};
        for (int k = 0; k < HB; k += 4) {
            float w0 = w_ihT[(k + 0) * G3 + gg];
            float w1 = w_ihT[(k + 1) * G3 + gg];
            float w2 = w_ihT[(k + 2) * G3 + gg];
            float w3 = w_ihT[(k + 3) * G3 + gg];
            #pragma unroll
            for (int s = 0; s < 8; ++s) {
                f32x4 ev = *(const f32x4*)&e[s][k];
                acc[s] += w0 * ev.x + w1 * ev.y + w2 * ev.z + w3 * ev.w;
            }
        }
        float bias = b_ih[gg] + (gg < 512 ? b_hh[gg] : 0.f);
        #pragma unroll
        for (int s = 0; s < 8; ++s)
            xp[(size_t)(tok0 + s) * G3 + gg] = acc[s] + bias;
    }
}

// ---------------------------------------------------------------- K2: GRU scan
// One workgroup, 4 waves, 1 wave/SIMD. With a single resident wave per SIMD,
// occupancy cannot improve by spilling -> the allocator gets the full 512-reg
// unified budget (256 VGPR + 256 AGPR; builtin MFMA reads A from either).
// Wave w owns hidden rows 64w..64w+63 for all 3 gates: A[3][4][8] = 384 regs,
// h-state 16, B-frags 32, acc 12, xp 12, misc ~30 -> ~490 <= 512, no spill.
// Per step (ONE barrier):
//   hoist 8 B-fragments (ds_read_b128) from double-buffered swizzled hbf
//   4 subtiles x {24 builtin MFMA -> in-lane gate math -> h-update}
//   h written bf16 to hbf[nxt] + global rnn.
__global__ __attribute__((amdgpu_waves_per_eu(1, 1))) __launch_bounds__(256)
void k_gru(const float* __restrict__ xp, const unsigned short* __restrict__ wfrag,
           const float* __restrict__ b_hh, unsigned short* __restrict__ rnn) {
    __shared__ unsigned short hbf[2][NBATCH][HB];    // 4096 B, XOR-swizzled
    __shared__ float bnL[HB];                        // 1024 B

    int tid = threadIdx.x;
    int w = tid >> 6, l = tid & 63;
    int c15 = l & 15, hi = l >> 4;
    int b4 = c15 & 3;
    int swz = (b4 & 1) << 6;

    // 96 A-fragments (lane-contiguous 16B loads, L2-resident after k_prep)
    bf16x8 A[3][4][8];
    #pragma unroll
    for (int g = 0; g < 3; ++g)
        #pragma unroll
        for (int s = 0; s < 4; ++s)
            #pragma unroll
            for (int c = 0; c < 8; ++c)
                A[g][s][c] = ((const bf16x8*)wfrag)[(((w * 3 + g) * 4 + s) * 8 + c) * 64 + l];

    for (int k = tid; k < 2 * NBATCH * HB; k += 256) ((unsigned short*)hbf)[k] = 0;
    if (tid < HB) bnL[tid] = b_hh[512 + tid];
    __syncthreads();

    float H[4][4];
    #pragma unroll
    for (int s = 0; s < 4; ++s)
        #pragma unroll
        for (int j = 0; j < 4; ++j) H[s][j] = 0.f;
    const f32x4 zz = {0.f, 0.f, 0.f, 0.f};

    int i0 = 64 * w + 4 * hi;                               // subtile-0 row base
    const float* xpb = xp + (size_t)b4 * SQ * G3 + i0;      // += G3 per step
    unsigned short* rnb = rnn + (size_t)b4 * SQ * HB + i0;  // += HB per step

    for (int t = 0; t < SQ; ++t) {
        int cur = t & 1, nxt = cur ^ 1;
        const char* hbb = (const char*)hbf + cur * 2048 + b4 * 512;

        // hoist the 8 h B-fragments for this step (shared by all 12 MFMA tiles)
        bf16x8 Bf[8];
        #pragma unroll
        for (int c = 0; c < 8; ++c)
            Bf[c] = *(const bf16x8*)(hbb + ((64 * c + 16 * hi) ^ swz));

        #pragma unroll
        for (int s = 0; s < 4; ++s) {
            // xp for this subtile: issued before the MFMA cluster, used after
            const float* xq = xpb + 16 * s;
            f32x4 xr = *(const f32x4*)(xq);
            f32x4 xz = *(const f32x4*)(xq + 256);
            f32x4 xn = *(const f32x4*)(xq + 512);

            f32x4 ar = zz, az = zz, an = zz;
            #pragma unroll
            for (int c = 0; c < 8; ++c) {
                ar = __builtin_amdgcn_mfma_f32_16x16x32_bf16(A[0][s][c], Bf[c], ar, 0, 0, 0);
                az = __builtin_amdgcn_mfma_f32_16x16x32_bf16(A[1][s][c], Bf[c], az, 0, 0, 0);
                an = __builtin_amdgcn_mfma_f32_16x16x32_bf16(A[2][s][c], Bf[c], an, 0, 0, 0);
            }
            // gate math: lane (c15,hi) owns rows i0 + 16s + j, batch b4
            int i0s = i0 + 16 * s;
            f32x4 bnv = *(const f32x4*)&bnL[i0s];
            u16x4 pack;
            #pragma unroll
            for (int j = 0; j < 4; ++j) {
                float r = sigm(xr[j] + ar[j]);
                float z = sigm(xz[j] + az[j]);
                float n = tanh_fast(xn[j] + r * (an[j] + bnv[j]));
                float hv = (1.f - z) * n + z * H[s][j];
                H[s][j] = hv;
                pack[j] = f2bf(hv);
            }
            if (c15 < 4) {
                *(u16x4*)((char*)hbf + nxt * 2048 + b4 * 512 + ((i0s * 2) ^ swz)) = pack;
                *(u16x4*)(rnb + 16 * s) = pack;
            }
        }
        __syncthreads();
        xpb += G3;
        rnb += HB;
    }
}

// ---------------------------------------------------------------- K3: logits
// [2048,256] bf16 @ [256,32000] bf16 -> fp32 + bias + mask. No LDS: A (1 MB)
// and B (16 MB) are L2/L3 resident; HBM-write-bound.
template <int CONV>
__global__ __launch_bounds__(256) void k_logits(
        const unsigned short* __restrict__ rnn, const unsigned short* __restrict__ woutbf,
        const float* __restrict__ woutf, const float* __restrict__ b_out,
        const int* __restrict__ x, float* __restrict__ out) {
    int tid = threadIdx.x;
    int wv = tid >> 6, l = tid & 63;
    int wm = wv >> 1, wn = wv & 1;
    int c15 = l & 15, hi = l >> 4;
    int m0 = blockIdx.y * 128 + wm * 64;
    int n0 = blockIdx.x * 128 + wn * 64;

    const f32x4 zz = {0.f, 0.f, 0.f, 0.f};
    f32x4 acc[4][4];
    #pragma unroll
    for (int i = 0; i < 4; ++i)
        #pragma unroll
        for (int j = 0; j < 4; ++j) acc[i][j] = zz;

    #pragma unroll
    for (int c = 0; c < 8; ++c) {
        bf16x8 af[4], bfr[4];
        #pragma unroll
        for (int rt = 0; rt < 4; ++rt)
            af[rt] = *(const bf16x8*)(rnn + (size_t)(m0 + rt * 16 + c15) * HB + 32 * c + 8 * hi);
        #pragma unroll
        for (int ct = 0; ct < 4; ++ct) {
            if (CONV) {
                const float* s = woutf + (size_t)(n0 + ct * 16 + c15) * HB + 32 * c + 8 * hi;
                f32x4 lo = *(const f32x4*)s, hi4 = *(const f32x4*)(s + 4);
                bf16x8 bb;
                #pragma unroll
                for (int q = 0; q < 4; ++q) bb[q] = (short)f2bf(lo[q]);
                #pragma unroll
                for (int q = 0; q < 4; ++q) bb[4 + q] = (short)f2bf(hi4[q]);
                bfr[ct] = bb;
            } else {
                bfr[ct] = *(const bf16x8*)(woutbf + (size_t)(n0 + ct * 16 + c15) * HB + 32 * c + 8 * hi);
            }
        }
        #pragma unroll
        for (int rt = 0; rt < 4; ++rt)
            #pragma unroll
            for (int ct = 0; ct < 4; ++ct)
                acc[rt][ct] = __builtin_amdgcn_mfma_f32_16x16x32_bf16(af[rt], bfr[ct], acc[rt][ct], 0, 0, 0);
    }

    float bo[4];
    #pragma unroll
    for (int ct = 0; ct < 4; ++ct) bo[ct] = b_out[n0 + ct * 16 + c15];

    const float NEGINF = -__builtin_inff();
    #pragma unroll
    for (int rt = 0; rt < 4; ++rt) {
        #pragma unroll
        for (int j = 0; j < 4; ++j) {
            int m = m0 + rt * 16 + 4 * hi + j;
            int tt = m & (SQ - 1);
            bool bad = (tt > 0) && (x[m - 1] == 0);
            float* orow = out + (size_t)m * NV;
            #pragma unroll
            for (int ct = 0; ct < 4; ++ct) {
                int v = n0 + ct * 16 + c15;
                float val = acc[rt][ct][j] + bo[ct];
                if (bad && v >= 3) val = NEGINF;
                orow[v] = val;
            }
        }
    }
}

extern "C" void kernel_launch(void* const* d_in, const int* in_sizes, int n_in,
                              void* d_out, int out_size, void* d_ws, size_t ws_size,
                              hipStream_t stream) {
    const int*   x     = (const int*)d_in[0];
    const float* emb   = (const float*)d_in[1];
    const float* W_ih  = (const float*)d_in[2];
    const float* W_hh  = (const float*)d_in[3];
    const float* b_ih  = (const float*)d_in[4];
    const float* b_hh  = (const float*)d_in[5];
    const float* W_out = (const float*)d_in[6];
    const float* b_out = (const float*)d_in[7];
    float* out = (float*)d_out;

    char* ws = (char*)d_ws;
    float*          xp     = (float*)(ws);                       // 6,291,456 B
    float*          w_ihT  = (float*)(ws + 6291456);             // 786,432 B
    unsigned short* wfrag  = (unsigned short*)(ws + 7077888);    // 393,216 B
    unsigned short* rnn    = (unsigned short*)(ws + 7471104);    // 1,048,576 B
    unsigned short* woutbf = (unsigned short*)(ws + 8519680);    // 16,384,000 B
    int use_woutbf = (ws_size >= (size_t)24903680) ? 1 : 0;

    k_prep<<<2048, 256, 0, stream>>>(W_ih, W_hh, W_out, w_ihT, wfrag, woutbf, use_woutbf);
    k_embed_xp<<<256, 256, 0, stream>>>(x, emb, w_ihT, b_ih, b_hh, xp);
    k_gru<<<1, 256, 0, stream>>>(xp, wfrag, b_hh, rnn);
    dim3 g3(NV / 128, 2048 / 128);
    if (use_woutbf)
        k_logits<0><<<g3, 256, 0, stream>>>(rnn, woutbf, nullptr, b_out, x, out);
    else
        k_logits<1><<<g3, 256, 0, stream>>>(rnn, nullptr, W_out, b_out, x, out);
}

// Round 8
// 1808.708 us; speedup vs baseline: 1.5183x; 1.0528x over previous
//
#include <hip/hip_runtime.h>
#include <hip/hip_bf16.h>

typedef __attribute__((ext_vector_type(8))) short bf16x8;
typedef __attribute__((ext_vector_type(4))) float f32x4;
typedef __attribute__((ext_vector_type(4))) unsigned short u16x4;

#define HB 256      // hidden
#define G3 768      // 3*H
#define SQ 512      // seq len
#define NBATCH 4
#define NV 32000

__device__ __forceinline__ unsigned short f2bf(float f) {
    unsigned int u = __float_as_uint(f);
    u = u + 0x7FFFu + ((u >> 16) & 1u);   // RNE
    return (unsigned short)(u >> 16);
}
__device__ __forceinline__ float sigm(float x) {
    return 1.0f / (1.0f + __expf(-x));
}
__device__ __forceinline__ float tanh_fast(float x) {
    // safe at +/-inf: 1 - 2/(e^{2x}+1)
    return 1.0f - 2.0f / (__expf(2.0f * x) + 1.0f);
}

// ---------------------------------------------------------------- K0: prep
// (a) W_ih^T fp32 [256][768] for coalesced K1 loads
// (b) W_hh -> bf16 MFMA A-fragments for the 4-wave k_gru:
//     layout [w:4][g:3][s:4][c:8][lane:64][i:8]
//     wave w owns hidden rows 64w..64w+63 (four 16-row subtiles s) per gate g
// (c) W_out -> bf16 (optional, if ws large enough)
__global__ void k_prep(const float* __restrict__ W_ih, const float* __restrict__ W_hh,
                       const float* __restrict__ W_out, float* __restrict__ w_ihT,
                       unsigned short* __restrict__ wfrag, unsigned short* __restrict__ woutbf,
                       int do_wout) {
    int stride = gridDim.x * blockDim.x;
    int tid = blockIdx.x * blockDim.x + threadIdx.x;
    for (int e = tid; e < G3 * HB; e += stride) {
        int k = e / G3, g = e - k * G3;
        w_ihT[e] = W_ih[g * HB + k];
    }
    for (int e = tid; e < G3 * HB; e += stride) {
        int i = e & 7, l = (e >> 3) & 63, c = (e >> 9) & 7, s = (e >> 12) & 3;
        int q = e >> 14;              // 0..11
        int g = q % 3, w = q / 3;     // gate, wave
        int row = g * 256 + 64 * w + 16 * s + (l & 15);
        int kk = 32 * c + 8 * (l >> 4) + i;
        wfrag[e] = f2bf(W_hh[row * HB + kk]);
    }
    if (do_wout) {
        for (int e = tid; e < NV * HB; e += stride) woutbf[e] = f2bf(W_out[e]);
    }
}

// ---------------------------------------------------------------- K1: embed + xp
__global__ __launch_bounds__(256) void k_embed_xp(
        const int* __restrict__ x, const float* __restrict__ emb,
        const float* __restrict__ w_ihT, const float* __restrict__ b_ih,
        const float* __restrict__ b_hh, float* __restrict__ xp) {
    __shared__ float e[8][HB];
    int tid = threadIdx.x;
    int tok0 = blockIdx.x * 8;
    {
        int s = tid >> 5, k0 = (tid & 31) * 8;
        long idx = x[tok0 + s];
        const float* src = emb + idx * (long)HB + k0;
        f32x4 a = *(const f32x4*)src, bq = *(const f32x4*)(src + 4);
        *(f32x4*)&e[s][k0] = a;
        *(f32x4*)&e[s][k0 + 4] = bq;
    }
    __syncthreads();
    #pragma unroll
    for (int it = 0; it < 3; ++it) {
        int gg = tid + it * 256;
        float acc[8] = {0.f, 0.f, 0.f, 0.f, 0.f, 0.f, 0.f, 0.f};
        for (int k = 0; k < HB; k += 4) {
            float w0 = w_ihT[(k + 0) * G3 + gg];
            float w1 = w_ihT[(k + 1) * G3 + gg];
            float w2 = w_ihT[(k + 2) * G3 + gg];
            float w3 = w_ihT[(k + 3) * G3 + gg];
            #pragma unroll
            for (int s = 0; s < 8; ++s) {
                f32x4 ev = *(const f32x4*)&e[s][k];
                acc[s] += w0 * ev.x + w1 * ev.y + w2 * ev.z + w3 * ev.w;
            }
        }
        float bias = b_ih[gg] + (gg < 512 ? b_hh[gg] : 0.f);
        #pragma unroll
        for (int s = 0; s < 8; ++s)
            xp[(size_t)(tok0 + s) * G3 + gg] = acc[s] + bias;
    }
}

// ---------------------------------------------------------------- K2: GRU scan
// One workgroup, 4 waves, 1 wave/SIMD (512-reg unified budget). Wave w owns
// hidden rows 64w..64w+63 for all 3 gates (96 A-fragments = 384 regs):
//   r/z gates (64 frags = 256 regs) -> AGPR, consumed DIRECTLY by inline-asm
//     v_mfma with "a" A-operand constraints (HW-legal on gfx950, zero moves)
//   n gate (32 frags = 128 regs)    -> VGPR, consumed by builtin MFMA
// Accumulators "+v". VGPR ~236 <= 256, AGPR = 256 -> no spill, no shuffling.
// Per step (ONE barrier): 8 ds_read Bf; 4 subtiles x {24 MFMA -> s_nop hazard
// guard -> in-lane gate math -> h}; h -> swizzled hbf[nxt] + global rnn.
__global__ __attribute__((amdgpu_waves_per_eu(1, 1))) __launch_bounds__(256)
void k_gru(const float* __restrict__ xp, const unsigned short* __restrict__ wfrag,
           const float* __restrict__ b_hh, unsigned short* __restrict__ rnn) {
    __shared__ unsigned short hbf[2][NBATCH][HB];    // 4096 B, XOR-swizzled

    int tid = threadIdx.x;
    int w = tid >> 6, l = tid & 63;
    int c15 = l & 15, hi = l >> 4;
    int b4 = c15 & 3;
    int swz = (b4 & 1) << 6;

    // A-fragments: r/z -> AGPR-pinned, n -> VGPR-pinned
    bf16x8 Arz[2][4][8];
    bf16x8 An[4][8];
    #pragma unroll
    for (int g = 0; g < 2; ++g)
        #pragma unroll
        for (int s = 0; s < 4; ++s)
            #pragma unroll
            for (int c = 0; c < 8; ++c) {
                Arz[g][s][c] = ((const bf16x8*)wfrag)[(((w * 3 + g) * 4 + s) * 8 + c) * 64 + l];
                asm volatile("" : "+a"(Arz[g][s][c]));
            }
    #pragma unroll
    for (int s = 0; s < 4; ++s)
        #pragma unroll
        for (int c = 0; c < 8; ++c) {
            An[s][c] = ((const bf16x8*)wfrag)[(((w * 3 + 2) * 4 + s) * 8 + c) * 64 + l];
            asm volatile("" : "+v"(An[s][c]));
        }

    for (int k = tid; k < 2 * NBATCH * HB; k += 256) ((unsigned short*)hbf)[k] = 0;

    int i0 = 64 * w + 4 * hi;                               // subtile-0 row base
    // n-gate bias, resident (replicated lanes hit same cache lines)
    f32x4 bnv[4];
    #pragma unroll
    for (int s = 0; s < 4; ++s) bnv[s] = *(const f32x4*)&b_hh[512 + i0 + 16 * s];

    float H[4][4];
    #pragma unroll
    for (int s = 0; s < 4; ++s)
        #pragma unroll
        for (int j = 0; j < 4; ++j) H[s][j] = 0.f;
    const f32x4 zz = {0.f, 0.f, 0.f, 0.f};

    const float* xpb = xp + (size_t)b4 * SQ * G3 + i0;      // += G3 per step
    unsigned short* rnb = rnn + (size_t)b4 * SQ * HB + i0;  // += HB per step
    __syncthreads();

    for (int t = 0; t < SQ; ++t) {
        int cur = t & 1, nxt = cur ^ 1;
        const char* hbb = (const char*)hbf + cur * 2048 + b4 * 512;

        // hoist the 8 h B-fragments for this step (shared by all 12 MFMA tiles)
        bf16x8 Bf[8];
        #pragma unroll
        for (int c = 0; c < 8; ++c)
            Bf[c] = *(const bf16x8*)(hbb + ((64 * c + 16 * hi) ^ swz));

        #pragma unroll
        for (int s = 0; s < 4; ++s) {
            // xp for this subtile: issued before the MFMA cluster, used after
            const float* xq = xpb + 16 * s;
            f32x4 xr = *(const f32x4*)(xq);
            f32x4 xz = *(const f32x4*)(xq + 256);
            f32x4 xn = *(const f32x4*)(xq + 512);

            f32x4 ar = zz, az = zz, an = zz;
            #pragma unroll
            for (int c = 0; c < 8; ++c) {
                asm("v_mfma_f32_16x16x32_bf16 %0, %1, %2, %0"
                    : "+v"(ar) : "a"(Arz[0][s][c]), "v"(Bf[c]));
                asm("v_mfma_f32_16x16x32_bf16 %0, %1, %2, %0"
                    : "+v"(az) : "a"(Arz[1][s][c]), "v"(Bf[c]));
                an = __builtin_amdgcn_mfma_f32_16x16x32_bf16(An[s][c], Bf[c], an, 0, 0, 0);
            }
            // MFMA -> VALU hazard guard for the asm-produced accumulators
            asm volatile("s_nop 7\n\ts_nop 7" : "+v"(ar), "+v"(az));

            // gate math: lane (c15,hi) owns rows i0 + 16s + j, batch b4
            int i0s = i0 + 16 * s;
            u16x4 pack;
            #pragma unroll
            for (int j = 0; j < 4; ++j) {
                float r = sigm(xr[j] + ar[j]);
                float z = sigm(xz[j] + az[j]);
                float n = tanh_fast(xn[j] + r * (an[j] + bnv[s][j]));
                float hv = (1.f - z) * n + z * H[s][j];
                H[s][j] = hv;
                pack[j] = f2bf(hv);
            }
            if (c15 < 4) {
                *(u16x4*)((char*)hbf + nxt * 2048 + b4 * 512 + ((i0s * 2) ^ swz)) = pack;
                *(u16x4*)(rnb + 16 * s) = pack;
            }
        }
        __syncthreads();
        xpb += G3;
        rnb += HB;
    }
}

// ---------------------------------------------------------------- K3: logits
// [2048,256] bf16 @ [256,32000] bf16 -> fp32 + bias + mask. No LDS: A (1 MB)
// and B (16 MB) are L2/L3 resident; HBM-write-bound.
template <int CONV>
__global__ __launch_bounds__(256) void k_logits(
        const unsigned short* __restrict__ rnn, const unsigned short* __restrict__ woutbf,
        const float* __restrict__ woutf, const float* __restrict__ b_out,
        const int* __restrict__ x, float* __restrict__ out) {
    int tid = threadIdx.x;
    int wv = tid >> 6, l = tid & 63;
    int wm = wv >> 1, wn = wv & 1;
    int c15 = l & 15, hi = l >> 4;
    int m0 = blockIdx.y * 128 + wm * 64;
    int n0 = blockIdx.x * 128 + wn * 64;

    const f32x4 zz = {0.f, 0.f, 0.f, 0.f};
    f32x4 acc[4][4];
    #pragma unroll
    for (int i = 0; i < 4; ++i)
        #pragma unroll
        for (int j = 0; j < 4; ++j) acc[i][j] = zz;

    #pragma unroll
    for (int c = 0; c < 8; ++c) {
        bf16x8 af[4], bfr[4];
        #pragma unroll
        for (int rt = 0; rt < 4; ++rt)
            af[rt] = *(const bf16x8*)(rnn + (size_t)(m0 + rt * 16 + c15) * HB + 32 * c + 8 * hi);
        #pragma unroll
        for (int ct = 0; ct < 4; ++ct) {
            if (CONV) {
                const float* s = woutf + (size_t)(n0 + ct * 16 + c15) * HB + 32 * c + 8 * hi;
                f32x4 lo = *(const f32x4*)s, hi4 = *(const f32x4*)(s + 4);
                bf16x8 bb;
                #pragma unroll
                for (int q = 0; q < 4; ++q) bb[q] = (short)f2bf(lo[q]);
                #pragma unroll
                for (int q = 0; q < 4; ++q) bb[4 + q] = (short)f2bf(hi4[q]);
                bfr[ct] = bb;
            } else {
                bfr[ct] = *(const bf16x8*)(woutbf + (size_t)(n0 + ct * 16 + c15) * HB + 32 * c + 8 * hi);
            }
        }
        #pragma unroll
        for (int rt = 0; rt < 4; ++rt)
            #pragma unroll
            for (int ct = 0; ct < 4; ++ct)
                acc[rt][ct] = __builtin_amdgcn_mfma_f32_16x16x32_bf16(af[rt], bfr[ct], acc[rt][ct], 0, 0, 0);
    }

    float bo[4];
    #pragma unroll
    for (int ct = 0; ct < 4; ++ct) bo[ct] = b_out[n0 + ct * 16 + c15];

    const float NEGINF = -__builtin_inff();
    #pragma unroll
    for (int rt = 0; rt < 4; ++rt) {
        #pragma unroll
        for (int j = 0; j < 4; ++j) {
            int m = m0 + rt * 16 + 4 * hi + j;
            int tt = m & (SQ - 1);
            bool bad = (tt > 0) && (x[m - 1] == 0);
            float* orow = out + (size_t)m * NV;
            #pragma unroll
            for (int ct = 0; ct < 4; ++ct) {
                int v = n0 + ct * 16 + c15;
                float val = acc[rt][ct][j] + bo[ct];
                if (bad && v >= 3) val = NEGINF;
                orow[v] = val;
            }
        }
    }
}

extern "C" void kernel_launch(void* const* d_in, const int* in_sizes, int n_in,
                              void* d_out, int out_size, void* d_ws, size_t ws_size,
                              hipStream_t stream) {
    const int*   x     = (const int*)d_in[0];
    const float* emb   = (const float*)d_in[1];
    const float* W_ih  = (const float*)d_in[2];
    const float* W_hh  = (const float*)d_in[3];
    const float* b_ih  = (const float*)d_in[4];
    const float* b_hh  = (const float*)d_in[5];
    const float* W_out = (const float*)d_in[6];
    const float* b_out = (const float*)d_in[7];
    float* out = (float*)d_out;

    char* ws = (char*)d_ws;
    float*          xp     = (float*)(ws);                       // 6,291,456 B
    float*          w_ihT  = (float*)(ws + 6291456);             // 786,432 B
    unsigned short* wfrag  = (unsigned short*)(ws + 7077888);    // 393,216 B
    unsigned short* rnn    = (unsigned short*)(ws + 7471104);    // 1,048,576 B
    unsigned short* woutbf = (unsigned short*)(ws + 8519680);    // 16,384,000 B
    int use_woutbf = (ws_size >= (size_t)24903680) ? 1 : 0;

    k_prep<<<2048, 256, 0, stream>>>(W_ih, W_hh, W_out, w_ihT, wfrag, woutbf, use_woutbf);
    k_embed_xp<<<256, 256, 0, stream>>>(x, emb, w_ihT, b_ih, b_hh, xp);
    k_gru<<<1, 256, 0, stream>>>(xp, wfrag, b_hh, rnn);
    dim3 g3(NV / 128, 2048 / 128);
    if (use_woutbf)
        k_logits<0><<<g3, 256, 0, stream>>>(rnn, woutbf, nullptr, b_out, x, out);
    else
        k_logits<1><<<g3, 256, 0, stream>>>(rnn, nullptr, W_out, b_out, x, out);
}

// Round 9
// 910.858 us; speedup vs baseline: 3.0150x; 1.9857x over previous
//
#include <hip/hip_runtime.h>
#include <hip/hip_bf16.h>

typedef __attribute__((ext_vector_type(8))) short bf16x8;
typedef __attribute__((ext_vector_type(4))) float f32x4;
typedef __attribute__((ext_vector_type(4))) unsigned short u16x4;

#define HB 256      // hidden
#define G3 768      // 3*H
#define SQ 512      // seq len
#define NBATCH 4
#define NV 32000

__device__ __forceinline__ unsigned short f2bf(float f) {
    unsigned int u = __float_as_uint(f);
    u = u + 0x7FFFu + ((u >> 16) & 1u);   // RNE
    return (unsigned short)(u >> 16);
}

// ---------------------------------------------------------------- K0: prep
// (a) W_ih^T fp32 [256][768] for coalesced K1 loads
// (b) W_hh -> bf16 MFMA A-fragments for the 4-wave k_gru:
//     layout [w:4][g:3][s:4][c:8][lane:64][i:8]
//     wave w owns hidden rows 64w..64w+63 (four 16-row subtiles s) per gate g
// (c) W_out -> bf16 (optional, if ws large enough)
__global__ void k_prep(const float* __restrict__ W_ih, const float* __restrict__ W_hh,
                       const float* __restrict__ W_out, float* __restrict__ w_ihT,
                       unsigned short* __restrict__ wfrag, unsigned short* __restrict__ woutbf,
                       int do_wout) {
    int stride = gridDim.x * blockDim.x;
    int tid = blockIdx.x * blockDim.x + threadIdx.x;
    for (int e = tid; e < G3 * HB; e += stride) {
        int k = e / G3, g = e - k * G3;
        w_ihT[e] = W_ih[g * HB + k];
    }
    for (int e = tid; e < G3 * HB; e += stride) {
        int i = e & 7, l = (e >> 3) & 63, c = (e >> 9) & 7, s = (e >> 12) & 3;
        int q = e >> 14;              // 0..11
        int g = q % 3, w = q / 3;     // gate, wave
        int row = g * 256 + 64 * w + 16 * s + (l & 15);
        int kk = 32 * c + 8 * (l >> 4) + i;
        wfrag[e] = f2bf(W_hh[row * HB + kk]);
    }
    if (do_wout) {
        for (int e = tid; e < NV * HB; e += stride) woutbf[e] = f2bf(W_out[e]);
    }
}

// ---------------------------------------------------------------- K1: embed + xp
__global__ __launch_bounds__(256) void k_embed_xp(
        const int* __restrict__ x, const float* __restrict__ emb,
        const float* __restrict__ w_ihT, const float* __restrict__ b_ih,
        const float* __restrict__ b_hh, float* __restrict__ xp) {
    __shared__ float e[8][HB];
    int tid = threadIdx.x;
    int tok0 = blockIdx.x * 8;
    {
        int s = tid >> 5, k0 = (tid & 31) * 8;
        long idx = x[tok0 + s];
        const float* src = emb + idx * (long)HB + k0;
        f32x4 a = *(const f32x4*)src, bq = *(const f32x4*)(src + 4);
        *(f32x4*)&e[s][k0] = a;
        *(f32x4*)&e[s][k0 + 4] = bq;
    }
    __syncthreads();
    #pragma unroll
    for (int it = 0; it < 3; ++it) {
        int gg = tid + it * 256;
        float acc[8] = {0.f, 0.f, 0.f, 0.f, 0.f, 0.f, 0.f, 0.f};
        for (int k = 0; k < HB; k += 4) {
            float w0 = w_ihT[(k + 0) * G3 + gg];
            float w1 = w_ihT[(k + 1) * G3 + gg];
            float w2 = w_ihT[(k + 2) * G3 + gg];
            float w3 = w_ihT[(k + 3) * G3 + gg];
            #pragma unroll
            for (int s = 0; s < 8; ++s) {
                f32x4 ev = *(const f32x4*)&e[s][k];
                acc[s] += w0 * ev.x + w1 * ev.y + w2 * ev.z + w3 * ev.w;
            }
        }
        float bias = b_ih[gg] + (gg < 512 ? b_hh[gg] : 0.f);
        #pragma unroll
        for (int s = 0; s < 8; ++s)
            xp[(size_t)(tok0 + s) * G3 + gg] = acc[s] + bias;
    }
}

// ---------------------------------------------------------------- K2: GRU scan
// One workgroup, 4 waves, 1 wave/SIMD (512-reg unified budget). Wave w owns
// hidden rows 64w..64w+63 for all 3 gates:
//   r/z A-fragments (64 = 256 regs) -> AGPR, inline-asm MFMA "a" operands
//   n  A-fragments (32 = 128 regs)  -> VGPR, builtin MFMA
// Per step (ONE barrier):
//   c-outer: 8 x {1 ds_read Bf; 12 MFMA (3 gates x 4 subtiles)}
//   s_nop hazard guard -> column-select acc[g4] (cndmask, no divergence)
//   ONE uniform 4-item gate block (rcp-based sigmoid/tanh)
//   all 64 lanes write distinct (batch,row) h -> swizzled hbf[nxt] + rnn.
__global__ __attribute__((amdgpu_waves_per_eu(1, 1))) __launch_bounds__(256)
void k_gru(const float* __restrict__ xp, const unsigned short* __restrict__ wfrag,
           const float* __restrict__ b_hh, unsigned short* __restrict__ rnn) {
    __shared__ unsigned short hbf[2][NBATCH][HB];    // 4096 B, XOR-swizzled

    int tid = threadIdx.x;
    int w = tid >> 6, l = tid & 63;
    int c15 = l & 15, hi = l >> 4;
    int b4 = c15 & 3;
    int g4 = c15 >> 2;
    int swz = (b4 & 1) << 6;

    // A-fragments: r/z -> AGPR-pinned, n -> VGPR-pinned
    bf16x8 Arz[2][4][8];
    bf16x8 An[4][8];
    #pragma unroll
    for (int g = 0; g < 2; ++g)
        #pragma unroll
        for (int s = 0; s < 4; ++s)
            #pragma unroll
            for (int c = 0; c < 8; ++c) {
                Arz[g][s][c] = ((const bf16x8*)wfrag)[(((w * 3 + g) * 4 + s) * 8 + c) * 64 + l];
                asm volatile("" : "+a"(Arz[g][s][c]));
            }
    #pragma unroll
    for (int s = 0; s < 4; ++s)
        #pragma unroll
        for (int c = 0; c < 8; ++c) {
            An[s][c] = ((const bf16x8*)wfrag)[(((w * 3 + 2) * 4 + c) * 8 + 0) * 64 + l];
            // NOTE: recompute proper index below (kept simple): overwritten next line
            An[s][c] = ((const bf16x8*)wfrag)[(((w * 3 + 2) * 4 + s) * 8 + c) * 64 + l];
            asm volatile("" : "+v"(An[s][c]));
        }

    for (int k = tid; k < 2 * NBATCH * HB; k += 256) ((unsigned short*)hbf)[k] = 0;

    int iL = 64 * w + 16 * g4 + 4 * hi;          // lane's 4 output rows iL..iL+3
    f32x4 bnv = *(const f32x4*)&b_hh[512 + iL];  // n-gate bias slice
    f32x4 H = {0.f, 0.f, 0.f, 0.f};
    const f32x4 zz = {0.f, 0.f, 0.f, 0.f};

    const float* xpb = xp + (size_t)b4 * SQ * G3 + iL;      // += G3 per step
    unsigned short* rnb = rnn + (size_t)b4 * SQ * HB + iL;  // += HB per step
    __syncthreads();

    for (int t = 0; t < SQ; ++t) {
        int cur = t & 1, nxt = cur ^ 1;
        const char* hbb = (const char*)hbf + cur * 2048 + b4 * 512;

        // xp slice for this lane's rows (hides under the MFMA cluster)
        f32x4 xr = *(const f32x4*)(xpb);
        f32x4 xz = *(const f32x4*)(xpb + 256);
        f32x4 xn = *(const f32x4*)(xpb + 512);

        f32x4 ar[4], az[4], an[4];
        #pragma unroll
        for (int s = 0; s < 4; ++s) { ar[s] = zz; az[s] = zz; an[s] = zz; }

        #pragma unroll
        for (int c = 0; c < 8; ++c) {
            bf16x8 Bf = *(const bf16x8*)(hbb + ((64 * c + 16 * hi) ^ swz));
            #pragma unroll
            for (int s = 0; s < 4; ++s) {
                asm("v_mfma_f32_16x16x32_bf16 %0, %1, %2, %0"
                    : "+v"(ar[s]) : "a"(Arz[0][s][c]), "v"(Bf));
                asm("v_mfma_f32_16x16x32_bf16 %0, %1, %2, %0"
                    : "+v"(az[s]) : "a"(Arz[1][s][c]), "v"(Bf));
                an[s] = __builtin_amdgcn_mfma_f32_16x16x32_bf16(An[s][c], Bf, an[s], 0, 0, 0);
            }
        }
        // MFMA -> VALU hazard guard for the asm-produced accumulators
        asm volatile("s_nop 7\n\ts_nop 7"
                     : "+v"(ar[0]), "+v"(ar[1]), "+v"(ar[2]), "+v"(ar[3]),
                       "+v"(az[0]), "+v"(az[1]), "+v"(az[2]), "+v"(az[3]));

        // column-select this lane's subtile accumulators (no divergence)
        bool s1 = (g4 & 1) != 0, s2 = (g4 & 2) != 0;
        f32x4 sAr = s2 ? (s1 ? ar[3] : ar[2]) : (s1 ? ar[1] : ar[0]);
        f32x4 sAz = s2 ? (s1 ? az[3] : az[2]) : (s1 ? az[1] : az[0]);
        f32x4 sAn = s2 ? (s1 ? an[3] : an[2]) : (s1 ? an[1] : an[0]);

        // gate math: lane owns rows iL..iL+3, batch b4 (uniform control)
        u16x4 pack;
        #pragma unroll
        for (int j = 0; j < 4; ++j) {
            float r = __builtin_amdgcn_rcpf(1.f + __expf(-(xr[j] + sAr[j])));
            float z = __builtin_amdgcn_rcpf(1.f + __expf(-(xz[j] + sAz[j])));
            float narg = xn[j] + r * (sAn[j] + bnv[j]);
            float n = 1.f - 2.f * __builtin_amdgcn_rcpf(__expf(2.f * narg) + 1.f);
            float hv = (1.f - z) * n + z * H[j];
            H[j] = hv;
            pack[j] = f2bf(hv);
        }
        *(u16x4*)((char*)hbf + nxt * 2048 + b4 * 512 + ((iL * 2) ^ swz)) = pack;
        *(u16x4*)rnb = pack;

        __syncthreads();
        xpb += G3;
        rnb += HB;
    }
}

// ---------------------------------------------------------------- K3: logits
// [2048,256] bf16 @ [256,32000] bf16 -> fp32 + bias + mask. No LDS: A (1 MB)
// and B (16 MB) are L2/L3 resident; HBM-write-bound.
template <int CONV>
__global__ __launch_bounds__(256) void k_logits(
        const unsigned short* __restrict__ rnn, const unsigned short* __restrict__ woutbf,
        const float* __restrict__ woutf, const float* __restrict__ b_out,
        const int* __restrict__ x, float* __restrict__ out) {
    int tid = threadIdx.x;
    int wv = tid >> 6, l = tid & 63;
    int wm = wv >> 1, wn = wv & 1;
    int c15 = l & 15, hi = l >> 4;
    int m0 = blockIdx.y * 128 + wm * 64;
    int n0 = blockIdx.x * 128 + wn * 64;

    const f32x4 zz = {0.f, 0.f, 0.f, 0.f};
    f32x4 acc[4][4];
    #pragma unroll
    for (int i = 0; i < 4; ++i)
        #pragma unroll
        for (int j = 0; j < 4; ++j) acc[i][j] = zz;

    #pragma unroll
    for (int c = 0; c < 8; ++c) {
        bf16x8 af[4], bfr[4];
        #pragma unroll
        for (int rt = 0; rt < 4; ++rt)
            af[rt] = *(const bf16x8*)(rnn + (size_t)(m0 + rt * 16 + c15) * HB + 32 * c + 8 * hi);
        #pragma unroll
        for (int ct = 0; ct < 4; ++ct) {
            if (CONV) {
                const float* s = woutf + (size_t)(n0 + ct * 16 + c15) * HB + 32 * c + 8 * hi;
                f32x4 lo = *(const f32x4*)s, hi4 = *(const f32x4*)(s + 4);
                bf16x8 bb;
                #pragma unroll
                for (int q = 0; q < 4; ++q) bb[q] = (short)f2bf(lo[q]);
                #pragma unroll
                for (int q = 0; q < 4; ++q) bb[4 + q] = (short)f2bf(hi4[q]);
                bfr[ct] = bb;
            } else {
                bfr[ct] = *(const bf16x8*)(woutbf + (size_t)(n0 + ct * 16 + c15) * HB + 32 * c + 8 * hi);
            }
        }
        #pragma unroll
        for (int rt = 0; rt < 4; ++rt)
            #pragma unroll
            for (int ct = 0; ct < 4; ++ct)
                acc[rt][ct] = __builtin_amdgcn_mfma_f32_16x16x32_bf16(af[rt], bfr[ct], acc[rt][ct], 0, 0, 0);
    }

    float bo[4];
    #pragma unroll
    for (int ct = 0; ct < 4; ++ct) bo[ct] = b_out[n0 + ct * 16 + c15];

    const float NEGINF = -__builtin_inff();
    #pragma unroll
    for (int rt = 0; rt < 4; ++rt) {
        #pragma unroll
        for (int j = 0; j < 4; ++j) {
            int m = m0 + rt * 16 + 4 * hi + j;
            int tt = m & (SQ - 1);
            bool bad = (tt > 0) && (x[m - 1] == 0);
            float* orow = out + (size_t)m * NV;
            #pragma unroll
            for (int ct = 0; ct < 4; ++ct) {
                int v = n0 + ct * 16 + c15;
                float val = acc[rt][ct][j] + bo[ct];
                if (bad && v >= 3) val = NEGINF;
                orow[v] = val;
            }
        }
    }
}

extern "C" void kernel_launch(void* const* d_in, const int* in_sizes, int n_in,
                              void* d_out, int out_size, void* d_ws, size_t ws_size,
                              hipStream_t stream) {
    const int*   x     = (const int*)d_in[0];
    const float* emb   = (const float*)d_in[1];
    const float* W_ih  = (const float*)d_in[2];
    const float* W_hh  = (const float*)d_in[3];
    const float* b_ih  = (const float*)d_in[4];
    const float* b_hh  = (const float*)d_in[5];
    const float* W_out = (const float*)d_in[6];
    const float* b_out = (const float*)d_in[7];
    float* out = (float*)d_out;

    char* ws = (char*)d_ws;
    float*          xp     = (float*)(ws);                       // 6,291,456 B
    float*          w_ihT  = (float*)(ws + 6291456);             // 786,432 B
    unsigned short* wfrag  = (unsigned short*)(ws + 7077888);    // 393,216 B
    unsigned short* rnn    = (unsigned short*)(ws + 7471104);    // 1,048,576 B
    unsigned short* woutbf = (unsigned short*)(ws + 8519680);    // 16,384,000 B
    int use_woutbf = (ws_size >= (size_t)24903680) ? 1 : 0;

    k_prep<<<2048, 256, 0, stream>>>(W_ih, W_hh, W_out, w_ihT, wfrag, woutbf, use_woutbf);
    k_embed_xp<<<256, 256, 0, stream>>>(x, emb, w_ihT, b_ih, b_hh, xp);
    k_gru<<<1, 256, 0, stream>>>(xp, wfrag, b_hh, rnn);
    dim3 g3(NV / 128, 2048 / 128);
    if (use_woutbf)
        k_logits<0><<<g3, 256, 0, stream>>>(rnn, woutbf, nullptr, b_out, x, out);
    else
        k_logits<1><<<g3, 256, 0, stream>>>(rnn, nullptr, W_out, b_out, x, out);
}

// Round 10
// 810.431 us; speedup vs baseline: 3.3886x; 1.1239x over previous
//
#include <hip/hip_runtime.h>
#include <hip/hip_bf16.h>

typedef __attribute__((ext_vector_type(8))) short bf16x8;
typedef __attribute__((ext_vector_type(4))) float f32x4;
typedef __attribute__((ext_vector_type(4))) unsigned short u16x4;

#define HB 256      // hidden
#define G3 768      // 3*H
#define SQ 512      // seq len
#define NBATCH 4
#define NV 32000

__device__ __forceinline__ unsigned short f2bf(float f) {
    unsigned int u = __float_as_uint(f);
    u = u + 0x7FFFu + ((u >> 16) & 1u);   // RNE
    return (unsigned short)(u >> 16);
}

// ---------------------------------------------------------------- K0: prep
// (a) W_ih^T fp32 [256][768] for coalesced K1 loads
// (b) W_hh -> bf16 MFMA A-fragments for the 4-wave k_gru:
//     layout [w:4][g:3][s:4][c:8][lane:64][i:8]
//     wave w owns hidden rows 64w..64w+63 (four 16-row subtiles s) per gate g
// (c) W_out -> bf16 (optional, if ws large enough)
__global__ void k_prep(const float* __restrict__ W_ih, const float* __restrict__ W_hh,
                       const float* __restrict__ W_out, float* __restrict__ w_ihT,
                       unsigned short* __restrict__ wfrag, unsigned short* __restrict__ woutbf,
                       int do_wout) {
    int stride = gridDim.x * blockDim.x;
    int tid = blockIdx.x * blockDim.x + threadIdx.x;
    for (int e = tid; e < G3 * HB; e += stride) {
        int k = e / G3, g = e - k * G3;
        w_ihT[e] = W_ih[g * HB + k];
    }
    for (int e = tid; e < G3 * HB; e += stride) {
        int i = e & 7, l = (e >> 3) & 63, c = (e >> 9) & 7, s = (e >> 12) & 3;
        int q = e >> 14;              // 0..11
        int g = q % 3, w = q / 3;     // gate, wave
        int row = g * 256 + 64 * w + 16 * s + (l & 15);
        int kk = 32 * c + 8 * (l >> 4) + i;
        wfrag[e] = f2bf(W_hh[row * HB + kk]);
    }
    if (do_wout) {
        for (int e = tid; e < NV * HB; e += stride) woutbf[e] = f2bf(W_out[e]);
    }
}

// ---------------------------------------------------------------- K1: embed + xp
__global__ __launch_bounds__(256) void k_embed_xp(
        const int* __restrict__ x, const float* __restrict__ emb,
        const float* __restrict__ w_ihT, const float* __restrict__ b_ih,
        const float* __restrict__ b_hh, float* __restrict__ xp) {
    __shared__ float e[8][HB];
    int tid = threadIdx.x;
    int tok0 = blockIdx.x * 8;
    {
        int s = tid >> 5, k0 = (tid & 31) * 8;
        long idx = x[tok0 + s];
        const float* src = emb + idx * (long)HB + k0;
        f32x4 a = *(const f32x4*)src, bq = *(const f32x4*)(src + 4);
        *(f32x4*)&e[s][k0] = a;
        *(f32x4*)&e[s][k0 + 4] = bq;
    }
    __syncthreads();
    #pragma unroll
    for (int it = 0; it < 3; ++it) {
        int gg = tid + it * 256;
        float acc[8] = {0.f, 0.f, 0.f, 0.f, 0.f, 0.f, 0.f, 0.f};
        for (int k = 0; k < HB; k += 4) {
            float w0 = w_ihT[(k + 0) * G3 + gg];
            float w1 = w_ihT[(k + 1) * G3 + gg];
            float w2 = w_ihT[(k + 2) * G3 + gg];
            float w3 = w_ihT[(k + 3) * G3 + gg];
            #pragma unroll
            for (int s = 0; s < 8; ++s) {
                f32x4 ev = *(const f32x4*)&e[s][k];
                acc[s] += w0 * ev.x + w1 * ev.y + w2 * ev.z + w3 * ev.w;
            }
        }
        float bias = b_ih[gg] + (gg < 512 ? b_hh[gg] : 0.f);
        #pragma unroll
        for (int s = 0; s < 8; ++s)
            xp[(size_t)(tok0 + s) * G3 + gg] = acc[s] + bias;
    }
}

// ---------------------------------------------------------------- K2: GRU scan
// One workgroup, 4 waves, 1 wave/SIMD (512-reg unified budget). Wave w owns
// hidden rows 64w..64w+63 for all 3 gates:
//   r/z A-fragments (64 = 256 regs) -> AGPR, inline-asm MFMA "a" operands
//   n  A-fragments (32 = 128 regs)  -> VGPR, builtin MFMA
// Per step (ONE barrier):
//   depth-2 rotated Bf reads: Bf[c+1] ds_read issued BEFORE c's 12 MFMAs
//   (hides the ~120-cyc LDS latency under the 192-cyc MFMA cluster)
//   s_nop hazard guard -> column-select acc[g4] (cndmask, no divergence)
//   ONE uniform 4-item gate block (rcp-based sigmoid/tanh)
//   all 64 lanes write distinct (batch,row) h -> swizzled hbf[nxt] + rnn.
__global__ __attribute__((amdgpu_waves_per_eu(1, 1))) __launch_bounds__(256)
void k_gru(const float* __restrict__ xp, const unsigned short* __restrict__ wfrag,
           const float* __restrict__ b_hh, unsigned short* __restrict__ rnn) {
    __shared__ unsigned short hbf[2][NBATCH][HB];    // 4096 B, XOR-swizzled

    int tid = threadIdx.x;
    int w = tid >> 6, l = tid & 63;
    int c15 = l & 15, hi = l >> 4;
    int b4 = c15 & 3;
    int g4 = c15 >> 2;
    int swz = (b4 & 1) << 6;

    // A-fragments: r/z -> AGPR-pinned, n -> VGPR-pinned
    bf16x8 Arz[2][4][8];
    bf16x8 An[4][8];
    #pragma unroll
    for (int g = 0; g < 2; ++g)
        #pragma unroll
        for (int s = 0; s < 4; ++s)
            #pragma unroll
            for (int c = 0; c < 8; ++c) {
                Arz[g][s][c] = ((const bf16x8*)wfrag)[(((w * 3 + g) * 4 + s) * 8 + c) * 64 + l];
                asm volatile("" : "+a"(Arz[g][s][c]));
            }
    #pragma unroll
    for (int s = 0; s < 4; ++s)
        #pragma unroll
        for (int c = 0; c < 8; ++c) {
            An[s][c] = ((const bf16x8*)wfrag)[(((w * 3 + 2) * 4 + s) * 8 + c) * 64 + l];
            asm volatile("" : "+v"(An[s][c]));
        }

    for (int k = tid; k < 2 * NBATCH * HB; k += 256) ((unsigned short*)hbf)[k] = 0;

    int iL = 64 * w + 16 * g4 + 4 * hi;          // lane's 4 output rows iL..iL+3
    f32x4 bnv = *(const f32x4*)&b_hh[512 + iL];  // n-gate bias slice
    f32x4 H = {0.f, 0.f, 0.f, 0.f};
    const f32x4 zz = {0.f, 0.f, 0.f, 0.f};

    const float* xpb = xp + (size_t)b4 * SQ * G3 + iL;      // += G3 per step
    unsigned short* rnb = rnn + (size_t)b4 * SQ * HB + iL;  // += HB per step
    __syncthreads();

    for (int t = 0; t < SQ; ++t) {
        int cur = t & 1, nxt = cur ^ 1;
        const char* hbb = (const char*)hbf + cur * 2048 + b4 * 512;

        // xp slice for this lane's rows (global; hides under the MFMA cluster)
        f32x4 xr = *(const f32x4*)(xpb);
        f32x4 xz = *(const f32x4*)(xpb + 256);
        f32x4 xn = *(const f32x4*)(xpb + 512);

        f32x4 ar[4], az[4], an[4];
        #pragma unroll
        for (int s = 0; s < 4; ++s) { ar[s] = zz; az[s] = zz; an[s] = zz; }

        // depth-2 rotated B-fragment pipeline: read c+1 before c's MFMAs
        bf16x8 BfA = *(const bf16x8*)(hbb + ((16 * hi) ^ swz));
        #pragma unroll
        for (int c = 0; c < 8; ++c) {
            bf16x8 BfN;
            if (c < 7)
                BfN = *(const bf16x8*)(hbb + ((64 * (c + 1) + 16 * hi) ^ swz));
            #pragma unroll
            for (int s = 0; s < 4; ++s) {
                asm("v_mfma_f32_16x16x32_bf16 %0, %1, %2, %0"
                    : "+v"(ar[s]) : "a"(Arz[0][s][c]), "v"(BfA));
                asm("v_mfma_f32_16x16x32_bf16 %0, %1, %2, %0"
                    : "+v"(az[s]) : "a"(Arz[1][s][c]), "v"(BfA));
                an[s] = __builtin_amdgcn_mfma_f32_16x16x32_bf16(An[s][c], BfA, an[s], 0, 0, 0);
            }
            if (c < 7) BfA = BfN;
        }
        // MFMA -> VALU hazard guard for the asm-produced accumulators
        asm volatile("s_nop 7\n\ts_nop 7"
                     : "+v"(ar[0]), "+v"(ar[1]), "+v"(ar[2]), "+v"(ar[3]),
                       "+v"(az[0]), "+v"(az[1]), "+v"(az[2]), "+v"(az[3]));

        // column-select this lane's subtile accumulators (no divergence)
        bool s1 = (g4 & 1) != 0, s2 = (g4 & 2) != 0;
        f32x4 sAr = s2 ? (s1 ? ar[3] : ar[2]) : (s1 ? ar[1] : ar[0]);
        f32x4 sAz = s2 ? (s1 ? az[3] : az[2]) : (s1 ? az[1] : az[0]);
        f32x4 sAn = s2 ? (s1 ? an[3] : an[2]) : (s1 ? an[1] : an[0]);

        // gate math: lane owns rows iL..iL+3, batch b4 (uniform control)
        u16x4 pack;
        #pragma unroll
        for (int j = 0; j < 4; ++j) {
            float r = __builtin_amdgcn_rcpf(1.f + __expf(-(xr[j] + sAr[j])));
            float z = __builtin_amdgcn_rcpf(1.f + __expf(-(xz[j] + sAz[j])));
            float narg = xn[j] + r * (sAn[j] + bnv[j]);
            float n = 1.f - 2.f * __builtin_amdgcn_rcpf(__expf(2.f * narg) + 1.f);
            float hv = (1.f - z) * n + z * H[j];
            H[j] = hv;
            pack[j] = f2bf(hv);
        }
        *(u16x4*)((char*)hbf + nxt * 2048 + b4 * 512 + ((iL * 2) ^ swz)) = pack;
        *(u16x4*)rnb = pack;

        __syncthreads();
        xpb += G3;
        rnb += HB;
    }
}

// ---------------------------------------------------------------- K3: logits
// [2048,256] bf16 @ [256,32000] bf16 -> fp32 + bias + mask. No LDS: A (1 MB)
// and B (16 MB) are L2/L3 resident; HBM-write-bound.
template <int CONV>
__global__ __launch_bounds__(256) void k_logits(
        const unsigned short* __restrict__ rnn, const unsigned short* __restrict__ woutbf,
        const float* __restrict__ woutf, const float* __restrict__ b_out,
        const int* __restrict__ x, float* __restrict__ out) {
    int tid = threadIdx.x;
    int wv = tid >> 6, l = tid & 63;
    int wm = wv >> 1, wn = wv & 1;
    int c15 = l & 15, hi = l >> 4;
    int m0 = blockIdx.y * 128 + wm * 64;
    int n0 = blockIdx.x * 128 + wn * 64;

    const f32x4 zz = {0.f, 0.f, 0.f, 0.f};
    f32x4 acc[4][4];
    #pragma unroll
    for (int i = 0; i < 4; ++i)
        #pragma unroll
        for (int j = 0; j < 4; ++j) acc[i][j] = zz;

    #pragma unroll
    for (int c = 0; c < 8; ++c) {
        bf16x8 af[4], bfr[4];
        #pragma unroll
        for (int rt = 0; rt < 4; ++rt)
            af[rt] = *(const bf16x8*)(rnn + (size_t)(m0 + rt * 16 + c15) * HB + 32 * c + 8 * hi);
        #pragma unroll
        for (int ct = 0; ct < 4; ++ct) {
            if (CONV) {
                const float* s = woutf + (size_t)(n0 + ct * 16 + c15) * HB + 32 * c + 8 * hi;
                f32x4 lo = *(const f32x4*)s, hi4 = *(const f32x4*)(s + 4);
                bf16x8 bb;
                #pragma unroll
                for (int q = 0; q < 4; ++q) bb[q] = (short)f2bf(lo[q]);
                #pragma unroll
                for (int q = 0; q < 4; ++q) bb[4 + q] = (short)f2bf(hi4[q]);
                bfr[ct] = bb;
            } else {
                bfr[ct] = *(const bf16x8*)(woutbf + (size_t)(n0 + ct * 16 + c15) * HB + 32 * c + 8 * hi);
            }
        }
        #pragma unroll
        for (int rt = 0; rt < 4; ++rt)
            #pragma unroll
            for (int ct = 0; ct < 4; ++ct)
                acc[rt][ct] = __builtin_amdgcn_mfma_f32_16x16x32_bf16(af[rt], bfr[ct], acc[rt][ct], 0, 0, 0);
    }

    float bo[4];
    #pragma unroll
    for (int ct = 0; ct < 4; ++ct) bo[ct] = b_out[n0 + ct * 16 + c15];

    const float NEGINF = -__builtin_inff();
    #pragma unroll
    for (int rt = 0; rt < 4; ++rt) {
        #pragma unroll
        for (int j = 0; j < 4; ++j) {
            int m = m0 + rt * 16 + 4 * hi + j;
            int tt = m & (SQ - 1);
            bool bad = (tt > 0) && (x[m - 1] == 0);
            float* orow = out + (size_t)m * NV;
            #pragma unroll
            for (int ct = 0; ct < 4; ++ct) {
                int v = n0 + ct * 16 + c15;
                float val = acc[rt][ct][j] + bo[ct];
                if (bad && v >= 3) val = NEGINF;
                orow[v] = val;
            }
        }
    }
}

extern "C" void kernel_launch(void* const* d_in, const int* in_sizes, int n_in,
                              void* d_out, int out_size, void* d_ws, size_t ws_size,
                              hipStream_t stream) {
    const int*   x     = (const int*)d_in[0];
    const float* emb   = (const float*)d_in[1];
    const float* W_ih  = (const float*)d_in[2];
    const float* W_hh  = (const float*)d_in[3];
    const float* b_ih  = (const float*)d_in[4];
    const float* b_hh  = (const float*)d_in[5];
    const float* W_out = (const float*)d_in[6];
    const float* b_out = (const float*)d_in[7];
    float* out = (float*)d_out;

    char* ws = (char*)d_ws;
    float*          xp     = (float*)(ws);                       // 6,291,456 B
    float*          w_ihT  = (float*)(ws + 6291456);             // 786,432 B
    unsigned short* wfrag  = (unsigned short*)(ws + 7077888);    // 393,216 B
    unsigned short* rnn    = (unsigned short*)(ws + 7471104);    // 1,048,576 B
    unsigned short* woutbf = (unsigned short*)(ws + 8519680);    // 16,384,000 B
    int use_woutbf = (ws_size >= (size_t)24903680) ? 1 : 0;

    k_prep<<<2048, 256, 0, stream>>>(W_ih, W_hh, W_out, w_ihT, wfrag, woutbf, use_woutbf);
    k_embed_xp<<<256, 256, 0, stream>>>(x, emb, w_ihT, b_ih, b_hh, xp);
    k_gru<<<1, 256, 0, stream>>>(xp, wfrag, b_hh, rnn);
    dim3 g3(NV / 128, 2048 / 128);
    if (use_woutbf)
        k_logits<0><<<g3, 256, 0, stream>>>(rnn, woutbf, nullptr, b_out, x, out);
    else
        k_logits<1><<<g3, 256, 0, stream>>>(rnn, nullptr, W_out, b_out, x, out);
}